// Round 8
// baseline (158.634 us; speedup 1.0000x reference)
//
#include <hip/hip_runtime.h>
#include <hip/hip_bf16.h>
#include <hip/hip_fp16.h>

#define HW 4096

typedef _Float16 f16x8 __attribute__((ext_vector_type(8)));
typedef float f32x4 __attribute__((ext_vector_type(4)));

#define FOR8(X) X(0) X(1) X(2) X(3) X(4) X(5) X(6) X(7)

static __device__ __forceinline__ __half2 u2h(unsigned int u) {
    union { unsigned int u; __half2 h; } c; c.u = u; return c.h;
}
static __device__ __forceinline__ unsigned int h2u(__half2 h) {
    union { unsigned int u; __half2 h; } c; c.h = h; return c.u;
}
static __device__ __forceinline__ f16x8 uint4_as_f16x8(uint4 v) {
    union { uint4 u; f16x8 f; } c; c.u = v; return c.f;
}

// ---------------- K0b: w3 -> fp16 MFMA A-fragment order ----------------
// w3h[p=(ic*8+oc)][lane][j] = fp16( w3[(ic*128+oc*16+od)*32 + m] ),
// od = lane&15, m = (lane>>4)*8 + j   (A-frag layout for mfma 16x16x32, HW-verified R4)
__global__ __launch_bounds__(256) void k0b_w3h(const float* __restrict__ w3, ushort* __restrict__ w3h) {
    int gi = blockIdx.x * 256 + threadIdx.x;       // 64*64*8 = 32768
    if (gi >= 32768) return;
    int j = gi & 7;
    int l = (gi >> 3) & 63;
    int p = gi >> 9;                                // ic*8+oc
    int ic = p >> 3, oc = p & 7;
    int od = l & 15;
    int m  = ((l >> 4) << 3) + j;
    __half h = __float2half(w3[(size_t)((ic * 128 + oc * 16 + od) * 32 + m)]);
    w3h[gi] = __half_as_ushort(h);
}

// ---------------- K0c: w2 -> fp16 MFMA A-fragment order ----------------
__global__ __launch_bounds__(256) void k0c_w2f(const float* __restrict__ w2, ushort* __restrict__ w2f) {
    int gi = blockIdx.x * 256 + threadIdx.x;       // 8*9*2*64*8 = 73728
    if (gi >= 73728) return;
    int j   = gi & 7;
    int l   = (gi >> 3) & 63;
    int h   = (gi >> 9) & 1;
    int tap = (gi >> 10) % 9;
    int g   = gi / 9216;
    int co = h * 16 + (l & 15);
    int ci = ((l >> 4) << 3) + j;
    float v = w2[(size_t)((g * 32 + co) * 32 + ci) * 9 + tap];
    w2f[gi] = __half_as_ushort(__float2half(v));
}

// ---------------- K1: relu(x) -> 1x1 conv (16->32 per group) -> relu -> h1g fp16 [b][g][px][32] ----------------
__global__ __launch_bounds__(256) void k1_conv1(const float* __restrict__ x, const float* __restrict__ w1,
                                                const float* __restrict__ b1, ushort* __restrict__ h1g) {
    int bi = blockIdx.x;                 // ((b*8 + g)*16 + chunk)
    int chunk = bi & 15;
    int g = (bi >> 4) & 7;
    int b = bi >> 7;
    int pos = chunk * 256 + threadIdx.x;

    const float* xb = x + (size_t)(b * 128 + g * 16) * HW + pos;
    float xv[16];
#pragma unroll
    for (int i = 0; i < 16; ++i) xv[i] = fmaxf(xb[i * HW], 0.f);

    const float* wg = w1 + g * 32 * 16;  // uniform across block -> scalar loads
    const float* bg = b1 + g * 32;
    ushort hv[32];
#pragma unroll
    for (int m = 0; m < 32; ++m) {
        float acc = bg[m];
#pragma unroll
        for (int i = 0; i < 16; ++i) acc = fmaf(xv[i], wg[m * 16 + i], acc);
        hv[m] = __half_as_ushort(__float2half(fmaxf(acc, 0.f)));
    }
    ushort* hb = h1g + ((size_t)(b * 8 + g) * HW + pos) * 32;
#pragma unroll
    for (int q = 0; q < 4; ++q) *(uint4*)&hb[q * 8] = *(uint4*)&hv[q * 8];
}

// ---------------- K2: grouped 3x3 SAME conv via MFMA (9 shifted 1x1 GEMMs), no LDS ----------------
__global__ __launch_bounds__(256) void k2_conv2(const ushort* __restrict__ h1g, const ushort* __restrict__ w2f,
                                                const float* __restrict__ b2, ushort* __restrict__ h2g) {
    int bi = blockIdx.x;                 // b*512 + g*64 + pt
    int pt = bi & 63;
    int g  = (bi >> 6) & 7;
    int b  = bi >> 9;
    int t  = threadIdx.x;
    int w  = t >> 6, l = t & 63;
    int pxbase = pt * 64 + w * 16;       // multiple of 16 -> same image row
    int kgrp = l >> 4;

    int y = pxbase >> 6;
    int x = (pxbase & 63) + (l & 15);

    const ushort* hbase = h1g + (size_t)(b * 8 + g) * HW * 32;
    f16x8 Bf[9];
#pragma unroll
    for (int dy = -1; dy <= 1; ++dy) {
        int yy = y + dy;
        int yyc = yy < 0 ? 0 : (yy > 63 ? 63 : yy);
        bool rv = (yy >= 0) && (yy < 64);
#pragma unroll
        for (int dx = -1; dx <= 1; ++dx) {
            int xx = x + dx;
            int xc = xx < 0 ? 0 : (xx > 63 ? 63 : xx);
            uint4 v = *(const uint4*)&hbase[((yyc << 6) + xc) * 32 + kgrp * 8];
            bool ok = rv && (xx >= 0) && (xx < 64);
            v.x = ok ? v.x : 0u; v.y = ok ? v.y : 0u;
            v.z = ok ? v.z : 0u; v.w = ok ? v.w : 0u;
            Bf[(dy + 1) * 3 + (dx + 1)] = uint4_as_f16x8(v);
        }
    }

    const ushort* wg = w2f + (size_t)g * 9216;     // [tap][h][64][8]
    f16x8 Af[9][2];
#pragma unroll
    for (int tap = 0; tap < 9; ++tap)
#pragma unroll
        for (int h = 0; h < 2; ++h)
            Af[tap][h] = *(const f16x8*)&wg[((tap * 2 + h) * 64 + l) * 8];

    f32x4 acc[2];
#pragma unroll
    for (int h = 0; h < 2; ++h) {
        float4 bias = *(const float4*)(b2 + g * 32 + h * 16 + kgrp * 4);
        acc[h][0] = bias.x; acc[h][1] = bias.y; acc[h][2] = bias.z; acc[h][3] = bias.w;
    }
#pragma unroll
    for (int tap = 0; tap < 9; ++tap) {
#pragma unroll
        for (int h = 0; h < 2; ++h)
            acc[h] = __builtin_amdgcn_mfma_f32_16x16x32_f16(Af[tap][h], Bf[tap], acc[h], 0, 0, 0);
    }

    int px = pxbase + (l & 15);
    ushort* ob = h2g + ((size_t)(b * 8 + g) * HW + px) * 32;
#pragma unroll
    for (int h = 0; h < 2; ++h) {
        __half2 lo = __floats2half2_rn(fmaxf(acc[h][0], 0.f), fmaxf(acc[h][1], 0.f));
        __half2 hi = __floats2half2_rn(fmaxf(acc[h][2], 0.f), fmaxf(acc[h][3], 0.f));
        uint2 wv; wv.x = h2u(lo); wv.y = h2u(hi);
        *(uint2*)&ob[h * 16 + kgrp * 4] = wv;
    }
}

// ---------------- K3: conv3 + routing fully in registers; no LDS, no arrays ----------------
// Block 256 thr = 4 waves; all waves share one 16-px tile; wave w owns oc = {2w, 2w+1}.
// Per oc: 8 MFMAs (ic=0..7) -> lane holds u[ic][od=lk*4..+3] for its px in named f32x4
// u0..u7. od-reductions = 2x shfl_xor(16,32); ic-reductions in-register. u stays f32.
__global__ __launch_bounds__(256) void k3_route(const ushort* __restrict__ h2g, const ushort* __restrict__ w3h,
                                                const float* __restrict__ b3, float* __restrict__ sOut,
                                                float* __restrict__ meanAcc) {
    int bid = blockIdx.x;
    int b   = bid >> 8;
    int px0 = (bid & 255) << 4;
    int t   = threadIdx.x;
    int w   = t >> 6, l = t & 63;
    int lk  = l >> 4;
    int px  = px0 + (l & 15);

    // persistent B-fragments (one per ic): 32 VGPRs
#define LOADB(i) f16x8 bf##i = *(const f16x8*)&h2g[(((size_t)(b * 8 + (i))) * HW + px) * 32 + lk * 8];
    FOR8(LOADB)
#undef LOADB

#pragma unroll
    for (int ocq = 0; ocq < 2; ++ocq) {
        int oc = w * 2 + ocq;

        // u_ic = W3[ic,oc] * h2[ic] + b3  (MFMA, C-init = bias)
#define COMPU(i) f32x4 u##i; { \
            f16x8 af = *(const f16x8*)&w3h[(((i) * 8 + oc) * 64 + l) * 8]; \
            float4 bv = *(const float4*)(b3 + (i) * 128 + oc * 16 + lk * 4); \
            f32x4 c0; c0[0] = bv.x; c0[1] = bv.y; c0[2] = bv.z; c0[3] = bv.w; \
            u##i = __builtin_amdgcn_mfma_f32_16x16x32_f16(af, bf##i, c0, 0, 0, 0); }
        FOR8(COMPU)
#undef COMPU

        // squash scale per ic:  sq = ||u_ic||^2 over 16 od (own 4 + lk-group butterfly)
#define COMPSC(i) float sc##i; { \
            float sp = u##i[0]*u##i[0] + u##i[1]*u##i[1] + u##i[2]*u##i[2] + u##i[3]*u##i[3]; \
            sp += __shfl_xor(sp, 16); sp += __shfl_xor(sp, 32); \
            sc##i = sp / ((0.5f + sp) * (sqrtf(sp + 1e-6f) + 1e-6f)); }
        FOR8(COMPSC)
#undef COMPSC

#define BRINIT(i) float br##i = 0.f;
        FOR8(BRINIT)
#undef BRINIT

#pragma unroll
        for (int it = 0; it < 2; ++it) {
#define CSC(i) float cs##i = sc##i / (1.f + __expf(-br##i));
            FOR8(CSC)
#undef CSC
            f32x4 sv = u0 * cs0;
            sv += u1 * cs1; sv += u2 * cs2; sv += u3 * cs3;
            sv += u4 * cs4; sv += u5 * cs5; sv += u6 * cs6; sv += u7 * cs7;
            float sp = sv[0]*sv[0] + sv[1]*sv[1] + sv[2]*sv[2] + sv[3]*sv[3];
            sp += __shfl_xor(sp, 16); sp += __shfl_xor(sp, 32);
            float f = sp / ((0.5f + sp) * (sqrtf(sp + 1e-6f) + 1e-6f));
#define DOTD(i) { \
            f32x4 pr = u##i * sv; \
            float dp = pr[0] + pr[1] + pr[2] + pr[3]; \
            dp += __shfl_xor(dp, 16); dp += __shfl_xor(dp, 32); \
            br##i = fmaf(sc##i * f, dp, br##i); }
            FOR8(DOTD)
#undef DOTD
        }

#define CF(i) float cf##i = 1.f / (1.f + __expf(-br##i));
        FOR8(CF)
#undef CF
        f32x4 s = u0 * cf0;
        s += u1 * cf1; s += u2 * cf2; s += u3 * cf3;
        s += u4 * cf4; s += u5 * cf5; s += u6 * cf6; s += u7 * cf7;

        // store s (od = lk*4 + comp)
        float* sb = sOut + ((size_t)((b * 8 + oc) * 16 + lk * 4)) * HW + px;
        sb[0] = s[0]; sb[HW] = s[1]; sb[(size_t)2 * HW] = s[2]; sb[(size_t)3 * HW] = s[3];

        // meanAcc: reduce over the 16 px lanes, atomics from lanes l&15==0
        float r0 = s[0], r1 = s[1], r2 = s[2], r3 = s[3];
#pragma unroll
        for (int m = 1; m < 16; m <<= 1) {
            r0 += __shfl_xor(r0, m); r1 += __shfl_xor(r1, m);
            r2 += __shfl_xor(r2, m); r3 += __shfl_xor(r3, m);
        }
        if ((l & 15) == 0) {
            float* ma = meanAcc + (b * 8 + oc) * 16 + lk * 4;
            atomicAdd(&ma[0], r0); atomicAdd(&ma[1], r1);
            atomicAdd(&ma[2], r2); atomicAdd(&ma[3], r3);
        }
    }
}

// ---------------- K4: avg = sum_od s*mean_hw; partial stats per (b,oc) ----------------
__global__ __launch_bounds__(256) void k4_avg(const float* __restrict__ sIn, const float* __restrict__ meanAcc,
                                              float* __restrict__ avg, float* __restrict__ stats) {
    int bi = blockIdx.x;                 // (b*8+oc)*16 + chunk
    int chunk = bi & 15;
    int bo = bi >> 4;
    int pos = chunk * 256 + threadIdx.x;

    const float* sb = sIn + (size_t)bo * 16 * HW + pos;
    const float* mh = meanAcc + bo * 16;
    float a = 0.f;
#pragma unroll
    for (int od = 0; od < 16; ++od) a = fmaf(sb[od * HW], mh[od] * (1.f / 4096.f), a);
    avg[(size_t)bo * HW + pos] = a;

    float s1 = a, s2 = a * a;
#pragma unroll
    for (int m = 1; m < 64; m <<= 1) {
        s1 += __shfl_xor(s1, m);
        s2 += __shfl_xor(s2, m);
    }
    if ((threadIdx.x & 63) == 0) {
        atomicAdd(&stats[bo * 2],     s1);
        atomicAdd(&stats[bo * 2 + 1], s2);
    }
}

// ---------------- K5: normalize, attn gate, residual ----------------
__global__ __launch_bounds__(256) void k5_out(const float* __restrict__ sIn, const float* __restrict__ x,
                                              const float* __restrict__ avg, const float* __restrict__ stats,
                                              const float* __restrict__ aw, const float* __restrict__ ab,
                                              float* __restrict__ out) {
    int bi = blockIdx.x;                 // (b*8+oc)*16 + chunk
    int chunk = bi & 15;
    int bo = bi >> 4;
    int oc = bo & 7;
    int pos = chunk * 256 + threadIdx.x;

    float sum = stats[bo * 2], sumsq = stats[bo * 2 + 1];
    float m   = sum * (1.f / 4096.f);
    float var = (sumsq - 4096.f * m * m) * (1.f / 4095.f);
    float sd  = sqrtf(fmaxf(var, 0.f)) + 1e-6f;

    float t   = (avg[(size_t)bo * HW + pos] - m) / sd * aw[oc] + ab[oc];
    float sig = 1.f / (1.f + __expf(-t));

    const float* sb = sIn + (size_t)bo * 16 * HW + pos;
    const float* xb = x   + (size_t)bo * 16 * HW + pos;   // bo*16 = b*128 + oc*16: matches x channel layout
    float* ob = out + (size_t)bo * 16 * HW + pos;
#pragma unroll
    for (int od = 0; od < 16; ++od) ob[od * HW] = fmaf(sb[od * HW], sig, xb[od * HW]);
}

extern "C" void kernel_launch(void* const* d_in, const int* in_sizes, int n_in,
                              void* d_out, int out_size, void* d_ws, size_t ws_size,
                              hipStream_t stream) {
    const float* x  = (const float*)d_in[0];
    const float* w1 = (const float*)d_in[1];
    const float* b1 = (const float*)d_in[2];
    const float* w2 = (const float*)d_in[3];
    const float* b2 = (const float*)d_in[4];
    const float* w3 = (const float*)d_in[5];
    const float* b3 = (const float*)d_in[6];
    const float* aw = (const float*)d_in[7];
    const float* ab = (const float*)d_in[8];

    float* ws      = (float*)d_ws;
    ushort* h1g    = (ushort*)ws;                    // 8,388,608 halfs  (4,194,304 floats)
    ushort* h2g    = (ushort*)(ws + 4194304);        // 8,388,608 halfs
    float* sbuf    = ws + 8388608;                   // 4,194,304 floats
    float* avg     = sbuf + 4194304;                 // 262,144
    float* meanAcc = avg + 262144;                   // 1024
    float* stats   = meanAcc + 1024;                 // 128
    ushort* w3h    = (ushort*)(stats + 128);         // 32,768 halfs = 16,384 floats
    ushort* w2f    = (ushort*)(stats + 128 + 16384); // 73,728 halfs = 36,864 floats

    hipMemsetAsync(meanAcc, 0, (1024 + 128) * sizeof(float), stream);
    k0b_w3h <<<128, 256, 0, stream>>>(w3, w3h);
    k0c_w2f <<<288, 256, 0, stream>>>(w2, w2f);
    k1_conv1<<<1024, 256, 0, stream>>>(x, w1, b1, h1g);
    k2_conv2<<<4096, 256, 0, stream>>>(h1g, w2f, b2, h2g);
    k3_route<<<2048, 256, 0, stream>>>(h2g, w3h, b3, sbuf, meanAcc);
    k4_avg  <<<1024, 256, 0, stream>>>(sbuf, meanAcc, avg, stats);
    k5_out  <<<1024, 256, 0, stream>>>(sbuf, x, avg, stats, aw, ab, (float*)d_out);
}